// Round 11
// baseline (249.094 us; speedup 1.0000x reference)
//
#include <hip/hip_runtime.h>

#define HH 1024
#define WW 1024
#define NB 4
#define NC 3
#define BC 12   // NB*NC
#define N1 255
#define N2 127
#define N3 63
#define N4 31
#define EPS 1e-5f

// ---------------- workspace layout (float offsets) ----------------
constexpr size_t S8_OFF  = 0;
constexpr size_t S8_SZ   = 4ull * BC * N1 * N1;   // raw sums g,s,gg,gs @255^2
constexpr size_t S16_OFF = S8_OFF + S8_SZ;
constexpr size_t S16_SZ  = 4ull * BC * N2 * N2;
constexpr size_t S32_OFF = S16_OFF + S16_SZ;
constexpr size_t S32_SZ  = 4ull * BC * N3 * N3;
constexpr size_t S64_OFF = S32_OFF + S32_SZ;
constexpr size_t S64_SZ  = 4ull * BC * N4 * N4;
constexpr size_t CV16_OFF = S64_OFF + S64_SZ;     // cov,var @127^2
constexpr size_t CV16_SZ  = 2ull * BC * N2 * N2;
constexpr size_t CV32_OFF = CV16_OFF + CV16_SZ;
constexpr size_t CV32_SZ  = 2ull * BC * N3 * N3;
constexpr size_t CV64_OFF = CV32_OFF + CV32_SZ;
constexpr size_t CV64_SZ  = 2ull * BC * N4 * N4;
constexpr size_t A_OFF    = CV64_OFF + CV64_SZ;   // A @ [B,3,255,255]
constexpr size_t A_SZ     = (size_t)NB * NC * N1 * N1;
constexpr size_t BB_OFF   = A_OFF + A_SZ;         // bb @ [B,3,255,255]
constexpr size_t WF_OFF   = BB_OFF + A_SZ;        // folded weights
// folded-weight sub-layout (row-major, R1 layout: wave-uniform s_load weights)
constexpr int WF_W1 = 0;              // 48*24 = 1152  (BN1 scale folded in)
constexpr int WF_B1 = 1152;           // 48            (BN1 bias folded)
constexpr int WF_W2 = 1200;           // 48*48 = 2304  (BN2 scale folded in)
constexpr int WF_B2 = 3504;           // 48
constexpr int WF_W3 = 3552;           // 3*48 = 144 -> 3696 floats total

// ---------------- kernel 0: fold BN into weights (one block) ----------------
__global__ __launch_bounds__(256) void prep_kernel(
    const float* __restrict__ w1, const float* __restrict__ g1,
    const float* __restrict__ b1, const float* __restrict__ rm1,
    const float* __restrict__ rv1,
    const float* __restrict__ w2, const float* __restrict__ g2,
    const float* __restrict__ b2, const float* __restrict__ rm2,
    const float* __restrict__ rv2,
    const float* __restrict__ w3, float* __restrict__ Wf)
{
    __shared__ float i1[48], i2[48];
    int t = threadIdx.x;
    if (t < 48) {
        float iv = g1[t] * rsqrtf(rv1[t] + EPS);
        i1[t] = iv;
        Wf[WF_B1 + t] = b1[t] - rm1[t] * iv;
        float iw = g2[t] * rsqrtf(rv2[t] + EPS);
        i2[t] = iw;
        Wf[WF_B2 + t] = b2[t] - rm2[t] * iw;
    }
    __syncthreads();
    for (int k = t; k < 48 * 24; k += 256) Wf[WF_W1 + k] = w1[k] * i1[k / 24];
    for (int k = t; k < 48 * 48; k += 256) Wf[WF_W2 + k] = w2[k] * i2[k / 48];
    for (int k = t; k < 3 * 48; k += 256)  Wf[WF_W3 + k] = w3[k];
}

// ---------------- kernel 1: 8x8 stride-4 box sums, 2 output rows/block ----------------
// Block = (bc, i2); computes output rows 2*i2 and 2*i2+1. The 12-row input
// strip is read ONCE: rows 0-3 -> out0, rows 4-7 -> both, rows 8-11 -> out1.
// Static unroll throughout (the 4-row variant's runtime-bounded loop was a
// measured regression). Row-sum reassociation ~1e-7 << 2e-3 tolerance.
__global__ __launch_bounds__(256) void base_kernel(
    const float* __restrict__ guide, const float* __restrict__ src,
    float* __restrict__ S8)
{
    int blk = blockIdx.x;
    int bc  = blk / 128;
    int i2  = blk % 128;
    int j   = threadIdx.x;
    if (j >= N1) return;

    int  row0 = 8 * i2;            // first input row of the strip
    bool two  = (i2 < 127);        // last group has only output row 254

    const float* g0 = guide + (size_t)bc * HH * WW + (size_t)row0 * WW + 4 * j;
    const float* s0 = src   + (size_t)bc * HH * WW + (size_t)row0 * WW + 4 * j;

    float sg0 = 0.f, ss0 = 0.f, sgg0 = 0.f, sgs0 = 0.f;
    float sg1 = 0.f, ss1 = 0.f, sgg1 = 0.f, sgs1 = 0.f;

#pragma unroll
    for (int rr = 0; rr < 8; ++rr) {
        float4 ga = *(const float4*)(g0 + (size_t)rr * WW);
        float4 gb = *(const float4*)(g0 + (size_t)rr * WW + 4);
        float4 sa = *(const float4*)(s0 + (size_t)rr * WW);
        float4 sb = *(const float4*)(s0 + (size_t)rr * WW + 4);
        float ge[8] = {ga.x, ga.y, ga.z, ga.w, gb.x, gb.y, gb.z, gb.w};
        float se[8] = {sa.x, sa.y, sa.z, sa.w, sb.x, sb.y, sb.z, sb.w};
        float rg = 0.f, rs = 0.f, rgg = 0.f, rgs = 0.f;
#pragma unroll
        for (int k = 0; k < 8; ++k) {
            float g = ge[k], s = se[k];
            rg  += g;
            rs  += s;
            rgg += g * g;
            rgs += g * s;
        }
        sg0 += rg; ss0 += rs; sgg0 += rgg; sgs0 += rgs;
        if (rr >= 4) { sg1 += rg; ss1 += rs; sgg1 += rgg; sgs1 += rgs; }
    }
    if (two) {
#pragma unroll
        for (int rr = 8; rr < 12; ++rr) {
            float4 ga = *(const float4*)(g0 + (size_t)rr * WW);
            float4 gb = *(const float4*)(g0 + (size_t)rr * WW + 4);
            float4 sa = *(const float4*)(s0 + (size_t)rr * WW);
            float4 sb = *(const float4*)(s0 + (size_t)rr * WW + 4);
            float ge[8] = {ga.x, ga.y, ga.z, ga.w, gb.x, gb.y, gb.z, gb.w};
            float se[8] = {sa.x, sa.y, sa.z, sa.w, sb.x, sb.y, sb.z, sb.w};
            float rg = 0.f, rs = 0.f, rgg = 0.f, rgs = 0.f;
#pragma unroll
            for (int k = 0; k < 8; ++k) {
                float g = ge[k], s = se[k];
                rg  += g;
                rs  += s;
                rgg += g * g;
                rgs += g * s;
            }
            sg1 += rg; ss1 += rs; sgg1 += rgg; sgs1 += rgs;
        }
    }

    size_t qs   = (size_t)BC * N1 * N1;
    size_t idx0 = (size_t)bc * N1 * N1 + (size_t)(2 * i2) * N1 + j;
    S8[0 * qs + idx0] = sg0;
    S8[1 * qs + idx0] = ss0;
    S8[2 * qs + idx0] = sgg0;
    S8[3 * qs + idx0] = sgs0;
    if (two) {
        size_t idx1 = idx0 + N1;
        S8[0 * qs + idx1] = sg1;
        S8[1 * qs + idx1] = ss1;
        S8[2 * qs + idx1] = sgg1;
        S8[3 * qs + idx1] = sgs1;
    }
}

// ---------------- kernel 2: pyramid level (raw sums + cov/var stats) ----------------
// Hierarchical chain (16 from 8, 32 from 16, 64 from 32): measured faster
// than single-dispatch direct summation (R8/R9: +16 us on clean totals).
__global__ __launch_bounds__(256) void pyr_kernel(
    const float* __restrict__ Sin, float* __restrict__ Sout,
    float* __restrict__ CVout, int nin, int nout, float invN)
{
    int idx = blockIdx.x * blockDim.x + threadIdx.x;
    int total = BC * nout * nout;
    if (idx >= total) return;
    int j  = idx % nout;
    int t  = idx / nout;
    int i  = t % nout;
    int bc = t / nout;

    size_t sIn  = (size_t)BC * nin * nin;
    size_t base = (size_t)bc * nin * nin;
    int p = 2 * i, q = 2 * j;

    float sums[4];
#pragma unroll
    for (int qt = 0; qt < 4; ++qt) {
        const float* P = Sin + (size_t)qt * sIn + base;
        sums[qt] = P[(size_t)p * nin + q] + P[(size_t)(p + 2) * nin + q] +
                   P[(size_t)p * nin + q + 2] + P[(size_t)(p + 2) * nin + q + 2];
    }
    size_t sOut = (size_t)BC * nout * nout;
    size_t o    = (size_t)bc * nout * nout + (size_t)i * nout + j;
    Sout[0 * sOut + o] = sums[0];
    Sout[1 * sOut + o] = sums[1];
    Sout[2 * sOut + o] = sums[2];
    Sout[3 * sOut + o] = sums[3];
    float mx = sums[0] * invN, my = sums[1] * invN;
    CVout[o]        = sums[3] * invN - mx * my;  // cov
    CVout[sOut + o] = sums[2] * invN - mx * mx;  // var
}

// ---------------- kernel 3: fused feature-gather + MLP + A/b ----------------
// 2 pixels/thread (idx, idx+HALF), SCALAR interleaved math: each wave-uniform
// s_load-ed weight feeds 2 independent FMA chains, halving the per-wave
// scalar-stream stalls that bound the 1-px variant (41 us, 56-59% VALUBusy).
// R2's version of this failed on a VGPR cap (84) + spill; fixed here with
// __launch_bounds__(256,2) (256-VGPR budget) and scalar (not v2f) state.
// Per-pixel arithmetic order identical to R1 -> bit-identical output.
__global__ __launch_bounds__(256, 2) void mlp_kernel(
    const float* __restrict__ S8,
    const float* __restrict__ CV16, const float* __restrict__ CV32,
    const float* __restrict__ CV64,
    const float* __restrict__ Wf,
    float* __restrict__ A, float* __restrict__ Bb)
{
    const float* __restrict__ W1 = Wf + WF_W1;
    const float* __restrict__ B1 = Wf + WF_B1;
    const float* __restrict__ W2 = Wf + WF_W2;
    const float* __restrict__ B2 = Wf + WF_B2;
    const float* __restrict__ W3 = Wf + WF_W3;

    constexpr int TOTAL = NB * N1 * N1;      // 260100
    constexpr int HALF  = TOTAL / 2;         // 130050
    int idx = blockIdx.x * 256 + threadIdx.x;
    if (idx >= HALF) return;

    float fe[2][24], fmx[2][3], fmy[2][3];
    size_t outo[2];

#pragma unroll
    for (int hfl = 0; hfl < 2; ++hfl) {
        int p  = idx + hfl * HALF;
        int ox = p % N1;
        int r  = p / N1;
        int oy = r % N1;
        int b  = r / N1;
        outo[hfl] = (size_t)(b * 3) * N1 * N1 + (size_t)oy * N1 + ox;

        // level 1 (r=8): stats inline from raw sums
        size_t s8q = (size_t)BC * N1 * N1;
#pragma unroll
        for (int c = 0; c < 3; ++c) {
            size_t o = outo[hfl] + (size_t)c * N1 * N1;
            float sg = S8[o], ss = S8[s8q + o];
            float sgg = S8[2 * s8q + o], sgs = S8[3 * s8q + o];
            float mx = sg * (1.f / 64.f), my = ss * (1.f / 64.f);
            fmx[hfl][c] = mx; fmy[hfl][c] = my;
            fe[hfl][c]     = sgs * (1.f / 64.f) - mx * my;
            fe[hfl][3 + c] = sgg * (1.f / 64.f) - mx * mx;
        }

        // levels 2..4: bilinear (align_corners) gather of cov/var
        const float* CVs[3] = {CV16, CV32, CV64};
        const int nins[3]   = {N2, N3, N4};
        const float scales[3] = {(float)(126.0 / 254.0), (float)(62.0 / 254.0),
                                 (float)(30.0 / 254.0)};
#pragma unroll
        for (int l = 0; l < 3; ++l) {
            const float* CV = CVs[l];
            int nin = nins[l];
            float sc = scales[l];
            float py = (float)oy * sc;
            int   i0 = min(max((int)floorf(py), 0), nin - 2);
            float wy = py - (float)i0;
            float px = (float)ox * sc;
            int   j0 = min(max((int)floorf(px), 0), nin - 2);
            float wx = px - (float)j0;
            size_t cvq = (size_t)BC * nin * nin;
            int fo = 6 + 6 * l;
#pragma unroll
            for (int c = 0; c < 3; ++c) {
                size_t bix = (size_t)((r / N1) * 3 + c) * nin * nin;  // b*3+c
                size_t o00 = bix + (size_t)i0 * nin + j0;
                float c00 = CV[o00], c01 = CV[o00 + 1];
                float c10 = CV[o00 + nin], c11 = CV[o00 + nin + 1];
                fe[hfl][fo + c] = (c00 * (1.f - wy) + c10 * wy) * (1.f - wx) +
                                  (c01 * (1.f - wy) + c11 * wy) * wx;
                float v00 = CV[cvq + o00], v01 = CV[cvq + o00 + 1];
                float v10 = CV[cvq + o00 + nin], v11 = CV[cvq + o00 + nin + 1];
                fe[hfl][fo + 3 + c] = (v00 * (1.f - wy) + v10 * wy) * (1.f - wx) +
                                      (v01 * (1.f - wy) + v11 * wy) * wx;
            }
        }
    }

    // layer 1: 24 -> 48, interleaved pixel pair (one weight, two FMAs)
    float h1a[48], h1b[48];
#pragma unroll
    for (int o = 0; o < 48; ++o) {
        float acc0 = B1[o], acc1 = acc0;
#pragma unroll
        for (int c = 0; c < 24; ++c) {
            float w = W1[o * 24 + c];
            acc0 = fmaf(w, fe[0][c], acc0);
            acc1 = fmaf(w, fe[1][c], acc1);
        }
        h1a[o] = fmaxf(acc0, 0.f);
        h1b[o] = fmaxf(acc1, 0.f);
    }

    // layers 2+3 fused: 48 -> 48 -> 3 (h2 never materialized; per-output
    // accumulation order over c and k unchanged -> bit-identical)
    float a30[3] = {0.f, 0.f, 0.f}, a31[3] = {0.f, 0.f, 0.f};
#pragma unroll
    for (int o = 0; o < 48; ++o) {
        float acc0 = B2[o], acc1 = acc0;
#pragma unroll
        for (int c = 0; c < 48; ++c) {
            float w = W2[o * 48 + c];
            acc0 = fmaf(w, h1a[c], acc0);
            acc1 = fmaf(w, h1b[c], acc1);
        }
        float h20 = fmaxf(acc0, 0.f), h21 = fmaxf(acc1, 0.f);
#pragma unroll
        for (int cc = 0; cc < 3; ++cc) {
            float w3v = W3[cc * 48 + o];
            a30[cc] = fmaf(w3v, h20, a30[cc]);
            a31[cc] = fmaf(w3v, h21, a31[cc]);
        }
    }

#pragma unroll
    for (int cc = 0; cc < 3; ++cc) {
        size_t o0 = outo[0] + (size_t)cc * N1 * N1;
        size_t o1 = outo[1] + (size_t)cc * N1 * N1;
        A[o0]  = a30[cc];
        Bb[o0] = fmy[0][cc] - a30[cc] * fmx[0][cc];
        A[o1]  = a31[cc];
        Bb[o1] = fmy[1][cc] - a31[cc] * fmx[1][cc];
    }
}

// ---------------- kernel 4: fused upsample + apply ----------------
// grid: BC*HH blocks (one image row each), 256 threads, 4 px/thread (float4)
__global__ __launch_bounds__(256) void final_kernel(
    const float* __restrict__ guide, const float* __restrict__ A,
    const float* __restrict__ Bb, float* __restrict__ out)
{
    __shared__ float aH[N1 + 1], bH[N1 + 1];
    int blk = blockIdx.x;
    int bc  = blk / HH;
    int h   = blk % HH;

    const float scale = (float)(254.0 / 1023.0);
    float py = (float)h * scale;
    int   i0 = min(max((int)floorf(py), 0), N1 - 2);
    float wy = py - (float)i0;

    int t = threadIdx.x;
    if (t < N1) {
        size_t base = (size_t)bc * N1 * N1 + (size_t)i0 * N1 + t;
        aH[t] = A[base] * (1.f - wy) + A[base + N1] * wy;
        bH[t] = Bb[base] * (1.f - wy) + Bb[base + N1] * wy;
    }
    __syncthreads();

    const float* gp = guide + (size_t)bc * HH * WW + (size_t)h * WW;
    float*       op = out   + (size_t)bc * HH * WW + (size_t)h * WW;

    float4 g4 = *(const float4*)(gp + 4 * t);
    float4 o4;
    float ge[4] = {g4.x, g4.y, g4.z, g4.w};
    float oe[4];
#pragma unroll
    for (int k = 0; k < 4; ++k) {
        int w = 4 * t + k;
        float px = (float)w * scale;
        int   j0 = min(max((int)floorf(px), 0), N1 - 2);
        float wx = px - (float)j0;
        float a = aH[j0] * (1.f - wx) + aH[j0 + 1] * wx;
        float bbv = bH[j0] * (1.f - wx) + bH[j0 + 1] * wx;
        oe[k] = a * ge[k] + bbv;
    }
    o4.x = oe[0]; o4.y = oe[1]; o4.z = oe[2]; o4.w = oe[3];
    *(float4*)(op + 4 * t) = o4;
}

// ---------------- launch ----------------
extern "C" void kernel_launch(void* const* d_in, const int* in_sizes, int n_in,
                              void* d_out, int out_size, void* d_ws, size_t ws_size,
                              hipStream_t stream)
{
    const float* guide = (const float*)d_in[0];
    const float* src   = (const float*)d_in[1];
    const float* w1    = (const float*)d_in[2];
    const float* g1    = (const float*)d_in[3];
    const float* b1    = (const float*)d_in[4];
    const float* rm1   = (const float*)d_in[5];
    const float* rv1   = (const float*)d_in[6];
    const float* w2    = (const float*)d_in[7];
    const float* g2    = (const float*)d_in[8];
    const float* b2    = (const float*)d_in[9];
    const float* rm2   = (const float*)d_in[10];
    const float* rv2   = (const float*)d_in[11];
    const float* w3    = (const float*)d_in[12];
    float*       out   = (float*)d_out;

    float* ws   = (float*)d_ws;
    float* S8   = ws + S8_OFF;
    float* S16  = ws + S16_OFF;
    float* S32  = ws + S32_OFF;
    float* S64  = ws + S64_OFF;
    float* CV16 = ws + CV16_OFF;
    float* CV32 = ws + CV32_OFF;
    float* CV64 = ws + CV64_OFF;
    float* Abuf = ws + A_OFF;
    float* Bbuf = ws + BB_OFF;
    float* Wf   = ws + WF_OFF;

    // 0. fold BN into weights (tiny, one block)
    prep_kernel<<<1, 256, 0, stream>>>(w1, g1, b1, rm1, rv1, w2, g2, b2, rm2, rv2,
                                       w3, Wf);

    // 1. base 8x8/s4 box sums (2 output rows per block)
    base_kernel<<<BC * 128, 256, 0, stream>>>(guide, src, S8);

    // 2. pyramid levels 16/32/64 (+ cov/var stats)
    {
        int total = BC * N2 * N2;
        pyr_kernel<<<(total + 255) / 256, 256, 0, stream>>>(S8, S16, CV16, N1, N2,
                                                            1.f / 256.f);
    }
    {
        int total = BC * N3 * N3;
        pyr_kernel<<<(total + 255) / 256, 256, 0, stream>>>(S16, S32, CV32, N2, N3,
                                                            1.f / 1024.f);
    }
    {
        int total = BC * N4 * N4;
        pyr_kernel<<<(total + 255) / 256, 256, 0, stream>>>(S32, S64, CV64, N3, N4,
                                                            1.f / 4096.f);
    }

    // 3. fused gather + MLP -> A, bb @255^2 (2 px/thread, 256-VGPR budget)
    {
        constexpr int HALF = (NB * N1 * N1) / 2;
        mlp_kernel<<<(HALF + 255) / 256, 256, 0, stream>>>(
            S8, CV16, CV32, CV64, Wf, Abuf, Bbuf);
    }

    // 4. fused upsample + apply
    final_kernel<<<BC * HH, 256, 0, stream>>>(guide, Abuf, Bbuf, out);
}

// Round 12
// 226.831 us; speedup vs baseline: 1.0982x; 1.0982x over previous
//
#include <hip/hip_runtime.h>

#define HH 1024
#define WW 1024
#define NB 4
#define NC 3
#define BC 12   // NB*NC
#define N1 255
#define N2 127
#define N3 63
#define N4 31
#define EPS 1e-5f

// ---------------- workspace layout (float offsets) ----------------
constexpr size_t S8_OFF  = 0;
constexpr size_t S8_SZ   = 4ull * BC * N1 * N1;   // raw sums g,s,gg,gs @255^2
constexpr size_t S16_OFF = S8_OFF + S8_SZ;
constexpr size_t S16_SZ  = 4ull * BC * N2 * N2;
constexpr size_t S32_OFF = S16_OFF + S16_SZ;
constexpr size_t S32_SZ  = 4ull * BC * N3 * N3;
constexpr size_t S64_OFF = S32_OFF + S32_SZ;
constexpr size_t S64_SZ  = 4ull * BC * N4 * N4;
constexpr size_t CV16_OFF = S64_OFF + S64_SZ;     // cov,var @127^2
constexpr size_t CV16_SZ  = 2ull * BC * N2 * N2;
constexpr size_t CV32_OFF = CV16_OFF + CV16_SZ;
constexpr size_t CV32_SZ  = 2ull * BC * N3 * N3;
constexpr size_t CV64_OFF = CV32_OFF + CV32_SZ;
constexpr size_t CV64_SZ  = 2ull * BC * N4 * N4;
constexpr size_t A_OFF    = CV64_OFF + CV64_SZ;   // A @ [B,3,255,255]
constexpr size_t A_SZ     = (size_t)NB * NC * N1 * N1;
constexpr size_t BB_OFF   = A_OFF + A_SZ;         // bb @ [B,3,255,255]
constexpr size_t WF_OFF   = BB_OFF + A_SZ;        // folded weights
// folded-weight sub-layout (row-major, R1 layout: wave-uniform s_load weights)
constexpr int WF_W1 = 0;              // 48*24 = 1152  (BN1 scale folded in)
constexpr int WF_B1 = 1152;           // 48            (BN1 bias folded)
constexpr int WF_W2 = 1200;           // 48*48 = 2304  (BN2 scale folded in)
constexpr int WF_B2 = 3504;           // 48
constexpr int WF_W3 = 3552;           // 3*48 = 144 -> 3696 floats total

// ---------------- kernel 0: fold BN into weights (one block) ----------------
__global__ __launch_bounds__(256) void prep_kernel(
    const float* __restrict__ w1, const float* __restrict__ g1,
    const float* __restrict__ b1, const float* __restrict__ rm1,
    const float* __restrict__ rv1,
    const float* __restrict__ w2, const float* __restrict__ g2,
    const float* __restrict__ b2, const float* __restrict__ rm2,
    const float* __restrict__ rv2,
    const float* __restrict__ w3, float* __restrict__ Wf)
{
    __shared__ float i1[48], i2[48];
    int t = threadIdx.x;
    if (t < 48) {
        float iv = g1[t] * rsqrtf(rv1[t] + EPS);
        i1[t] = iv;
        Wf[WF_B1 + t] = b1[t] - rm1[t] * iv;
        float iw = g2[t] * rsqrtf(rv2[t] + EPS);
        i2[t] = iw;
        Wf[WF_B2 + t] = b2[t] - rm2[t] * iw;
    }
    __syncthreads();
    for (int k = t; k < 48 * 24; k += 256) Wf[WF_W1 + k] = w1[k] * i1[k / 24];
    for (int k = t; k < 48 * 48; k += 256) Wf[WF_W2 + k] = w2[k] * i2[k / 48];
    for (int k = t; k < 3 * 48; k += 256)  Wf[WF_W3 + k] = w3[k];
}

// ---------------- kernel 1: 8x8 stride-4 box sums, 2 output rows/block ----------------
// Block = (bc, i2); computes output rows 2*i2 and 2*i2+1. The 12-row input
// strip is read ONCE: rows 0-3 -> out0, rows 4-7 -> both, rows 8-11 -> out1.
// Static unroll throughout (the 4-row variant's runtime-bounded loop was a
// measured regression). Row-sum reassociation ~1e-7 << 2e-3 tolerance.
__global__ __launch_bounds__(256) void base_kernel(
    const float* __restrict__ guide, const float* __restrict__ src,
    float* __restrict__ S8)
{
    int blk = blockIdx.x;
    int bc  = blk / 128;
    int i2  = blk % 128;
    int j   = threadIdx.x;
    if (j >= N1) return;

    int  row0 = 8 * i2;            // first input row of the strip
    bool two  = (i2 < 127);        // last group has only output row 254

    const float* g0 = guide + (size_t)bc * HH * WW + (size_t)row0 * WW + 4 * j;
    const float* s0 = src   + (size_t)bc * HH * WW + (size_t)row0 * WW + 4 * j;

    float sg0 = 0.f, ss0 = 0.f, sgg0 = 0.f, sgs0 = 0.f;
    float sg1 = 0.f, ss1 = 0.f, sgg1 = 0.f, sgs1 = 0.f;

#pragma unroll
    for (int rr = 0; rr < 8; ++rr) {
        float4 ga = *(const float4*)(g0 + (size_t)rr * WW);
        float4 gb = *(const float4*)(g0 + (size_t)rr * WW + 4);
        float4 sa = *(const float4*)(s0 + (size_t)rr * WW);
        float4 sb = *(const float4*)(s0 + (size_t)rr * WW + 4);
        float ge[8] = {ga.x, ga.y, ga.z, ga.w, gb.x, gb.y, gb.z, gb.w};
        float se[8] = {sa.x, sa.y, sa.z, sa.w, sb.x, sb.y, sb.z, sb.w};
        float rg = 0.f, rs = 0.f, rgg = 0.f, rgs = 0.f;
#pragma unroll
        for (int k = 0; k < 8; ++k) {
            float g = ge[k], s = se[k];
            rg  += g;
            rs  += s;
            rgg += g * g;
            rgs += g * s;
        }
        sg0 += rg; ss0 += rs; sgg0 += rgg; sgs0 += rgs;
        if (rr >= 4) { sg1 += rg; ss1 += rs; sgg1 += rgg; sgs1 += rgs; }
    }
    if (two) {
#pragma unroll
        for (int rr = 8; rr < 12; ++rr) {
            float4 ga = *(const float4*)(g0 + (size_t)rr * WW);
            float4 gb = *(const float4*)(g0 + (size_t)rr * WW + 4);
            float4 sa = *(const float4*)(s0 + (size_t)rr * WW);
            float4 sb = *(const float4*)(s0 + (size_t)rr * WW + 4);
            float ge[8] = {ga.x, ga.y, ga.z, ga.w, gb.x, gb.y, gb.z, gb.w};
            float se[8] = {sa.x, sa.y, sa.z, sa.w, sb.x, sb.y, sb.z, sb.w};
            float rg = 0.f, rs = 0.f, rgg = 0.f, rgs = 0.f;
#pragma unroll
            for (int k = 0; k < 8; ++k) {
                float g = ge[k], s = se[k];
                rg  += g;
                rs  += s;
                rgg += g * g;
                rgs += g * s;
            }
            sg1 += rg; ss1 += rs; sgg1 += rgg; sgs1 += rgs;
        }
    }

    size_t qs   = (size_t)BC * N1 * N1;
    size_t idx0 = (size_t)bc * N1 * N1 + (size_t)(2 * i2) * N1 + j;
    S8[0 * qs + idx0] = sg0;
    S8[1 * qs + idx0] = ss0;
    S8[2 * qs + idx0] = sgg0;
    S8[3 * qs + idx0] = sgs0;
    if (two) {
        size_t idx1 = idx0 + N1;
        S8[0 * qs + idx1] = sg1;
        S8[1 * qs + idx1] = ss1;
        S8[2 * qs + idx1] = sgg1;
        S8[3 * qs + idx1] = sgs1;
    }
}

// ---------------- kernel 2: pyramid level (raw sums + cov/var stats) ----------------
// Hierarchical chain (16 from 8, 32 from 16, 64 from 32): measured faster
// than single-dispatch direct summation (R8/R9: +16 us on clean totals).
__global__ __launch_bounds__(256) void pyr_kernel(
    const float* __restrict__ Sin, float* __restrict__ Sout,
    float* __restrict__ CVout, int nin, int nout, float invN)
{
    int idx = blockIdx.x * blockDim.x + threadIdx.x;
    int total = BC * nout * nout;
    if (idx >= total) return;
    int j  = idx % nout;
    int t  = idx / nout;
    int i  = t % nout;
    int bc = t / nout;

    size_t sIn  = (size_t)BC * nin * nin;
    size_t base = (size_t)bc * nin * nin;
    int p = 2 * i, q = 2 * j;

    float sums[4];
#pragma unroll
    for (int qt = 0; qt < 4; ++qt) {
        const float* P = Sin + (size_t)qt * sIn + base;
        sums[qt] = P[(size_t)p * nin + q] + P[(size_t)(p + 2) * nin + q] +
                   P[(size_t)p * nin + q + 2] + P[(size_t)(p + 2) * nin + q + 2];
    }
    size_t sOut = (size_t)BC * nout * nout;
    size_t o    = (size_t)bc * nout * nout + (size_t)i * nout + j;
    Sout[0 * sOut + o] = sums[0];
    Sout[1 * sOut + o] = sums[1];
    Sout[2 * sOut + o] = sums[2];
    Sout[3 * sOut + o] = sums[3];
    float mx = sums[0] * invN, my = sums[1] * invN;
    CVout[o]        = sums[3] * invN - mx * my;  // cov
    CVout[sOut + o] = sums[2] * invN - mx * mx;  // var
}

// ---------------- kernel 3: fused feature-gather + MLP + A/b (R1 exact) ----------------
// Row-major weights, wave-uniform compile-time indices -> s_load/SGPR path.
// Best-measured variant across 7 tested alternatives (41 us; LDS 54, packed
// 49, VMEM 149, transposed 43, thread-split 149, 2-px 105); do not perturb.
__global__ __launch_bounds__(256) void mlp_kernel(
    const float* __restrict__ S8,
    const float* __restrict__ CV16, const float* __restrict__ CV32,
    const float* __restrict__ CV64,
    const float* __restrict__ Wf,
    float* __restrict__ A, float* __restrict__ Bb)
{
    const float* __restrict__ W1 = Wf + WF_W1;
    const float* __restrict__ B1 = Wf + WF_B1;
    const float* __restrict__ W2 = Wf + WF_W2;
    const float* __restrict__ B2 = Wf + WF_B2;
    const float* __restrict__ W3 = Wf + WF_W3;

    int idx = blockIdx.x * 256 + threadIdx.x;
    if (idx >= NB * N1 * N1) return;
    int ox = idx % N1;
    int r  = idx / N1;
    int oy = r % N1;
    int b  = r / N1;

    float feats[24], mx1[3], my1[3];

    // level 1 (r=8): stats inline from raw sums
    size_t s8q = (size_t)BC * N1 * N1;
    for (int c = 0; c < 3; ++c) {
        size_t o = (size_t)(b * 3 + c) * N1 * N1 + (size_t)oy * N1 + ox;
        float sg = S8[o], ss = S8[s8q + o], sgg = S8[2 * s8q + o], sgs = S8[3 * s8q + o];
        float mx = sg * (1.f / 64.f), my = ss * (1.f / 64.f);
        mx1[c] = mx; my1[c] = my;
        feats[c]     = sgs * (1.f / 64.f) - mx * my;
        feats[3 + c] = sgg * (1.f / 64.f) - mx * mx;
    }

    // levels 2..4: bilinear (align_corners) gather of cov/var
    const float* CVs[3] = {CV16, CV32, CV64};
    const int nins[3]   = {N2, N3, N4};
    const float scales[3] = {(float)(126.0 / 254.0), (float)(62.0 / 254.0),
                             (float)(30.0 / 254.0)};
#pragma unroll
    for (int l = 0; l < 3; ++l) {
        const float* CV = CVs[l];
        int nin = nins[l];
        float sc = scales[l];
        float py = (float)oy * sc;
        int   i0 = min(max((int)floorf(py), 0), nin - 2);
        float wy = py - (float)i0;
        float px = (float)ox * sc;
        int   j0 = min(max((int)floorf(px), 0), nin - 2);
        float wx = px - (float)j0;
        size_t cvq = (size_t)BC * nin * nin;
        int fo = 6 + 6 * l;
        for (int c = 0; c < 3; ++c) {
            size_t bix = (size_t)(b * 3 + c) * nin * nin;
            size_t o00 = bix + (size_t)i0 * nin + j0;
            // cov
            float c00 = CV[o00], c01 = CV[o00 + 1];
            float c10 = CV[o00 + nin], c11 = CV[o00 + nin + 1];
            feats[fo + c] = (c00 * (1.f - wy) + c10 * wy) * (1.f - wx) +
                            (c01 * (1.f - wy) + c11 * wy) * wx;
            // var
            float v00 = CV[cvq + o00], v01 = CV[cvq + o00 + 1];
            float v10 = CV[cvq + o00 + nin], v11 = CV[cvq + o00 + nin + 1];
            feats[fo + 3 + c] = (v00 * (1.f - wy) + v10 * wy) * (1.f - wx) +
                                (v01 * (1.f - wy) + v11 * wy) * wx;
        }
    }

    // MLP: 24 -> 48 -> 48 -> 3 (BN already folded into W/B)
    float h1[48];
#pragma unroll
    for (int o = 0; o < 48; ++o) {
        float acc = B1[o];
#pragma unroll
        for (int c = 0; c < 24; ++c) acc = fmaf(W1[o * 24 + c], feats[c], acc);
        h1[o] = fmaxf(acc, 0.f);
    }
    float h2[48];
#pragma unroll
    for (int o = 0; o < 48; ++o) {
        float acc = B2[o];
#pragma unroll
        for (int c = 0; c < 48; ++c) acc = fmaf(W2[o * 48 + c], h1[c], acc);
        h2[o] = fmaxf(acc, 0.f);
    }
#pragma unroll
    for (int c = 0; c < 3; ++c) {
        float acc = 0.f;
#pragma unroll
        for (int k = 0; k < 48; ++k) acc = fmaf(W3[c * 48 + k], h2[k], acc);
        size_t o = (size_t)(b * 3 + c) * N1 * N1 + (size_t)oy * N1 + ox;
        A[o]  = acc;
        Bb[o] = my1[c] - acc * mx1[c];
    }
}

// ---------------- kernel 4: fused upsample + apply ----------------
// grid: BC*HH blocks (one image row each), 256 threads, 4 px/thread (float4)
__global__ __launch_bounds__(256) void final_kernel(
    const float* __restrict__ guide, const float* __restrict__ A,
    const float* __restrict__ Bb, float* __restrict__ out)
{
    __shared__ float aH[N1 + 1], bH[N1 + 1];
    int blk = blockIdx.x;
    int bc  = blk / HH;
    int h   = blk % HH;

    const float scale = (float)(254.0 / 1023.0);
    float py = (float)h * scale;
    int   i0 = min(max((int)floorf(py), 0), N1 - 2);
    float wy = py - (float)i0;

    int t = threadIdx.x;
    if (t < N1) {
        size_t base = (size_t)bc * N1 * N1 + (size_t)i0 * N1 + t;
        aH[t] = A[base] * (1.f - wy) + A[base + N1] * wy;
        bH[t] = Bb[base] * (1.f - wy) + Bb[base + N1] * wy;
    }
    __syncthreads();

    const float* gp = guide + (size_t)bc * HH * WW + (size_t)h * WW;
    float*       op = out   + (size_t)bc * HH * WW + (size_t)h * WW;

    float4 g4 = *(const float4*)(gp + 4 * t);
    float4 o4;
    float ge[4] = {g4.x, g4.y, g4.z, g4.w};
    float oe[4];
#pragma unroll
    for (int k = 0; k < 4; ++k) {
        int w = 4 * t + k;
        float px = (float)w * scale;
        int   j0 = min(max((int)floorf(px), 0), N1 - 2);
        float wx = px - (float)j0;
        float a = aH[j0] * (1.f - wx) + aH[j0 + 1] * wx;
        float bbv = bH[j0] * (1.f - wx) + bH[j0 + 1] * wx;
        oe[k] = a * ge[k] + bbv;
    }
    o4.x = oe[0]; o4.y = oe[1]; o4.z = oe[2]; o4.w = oe[3];
    *(float4*)(op + 4 * t) = o4;
}

// ---------------- launch ----------------
extern "C" void kernel_launch(void* const* d_in, const int* in_sizes, int n_in,
                              void* d_out, int out_size, void* d_ws, size_t ws_size,
                              hipStream_t stream)
{
    const float* guide = (const float*)d_in[0];
    const float* src   = (const float*)d_in[1];
    const float* w1    = (const float*)d_in[2];
    const float* g1    = (const float*)d_in[3];
    const float* b1    = (const float*)d_in[4];
    const float* rm1   = (const float*)d_in[5];
    const float* rv1   = (const float*)d_in[6];
    const float* w2    = (const float*)d_in[7];
    const float* g2    = (const float*)d_in[8];
    const float* b2    = (const float*)d_in[9];
    const float* rm2   = (const float*)d_in[10];
    const float* rv2   = (const float*)d_in[11];
    const float* w3    = (const float*)d_in[12];
    float*       out   = (float*)d_out;

    float* ws   = (float*)d_ws;
    float* S8   = ws + S8_OFF;
    float* S16  = ws + S16_OFF;
    float* S32  = ws + S32_OFF;
    float* S64  = ws + S64_OFF;
    float* CV16 = ws + CV16_OFF;
    float* CV32 = ws + CV32_OFF;
    float* CV64 = ws + CV64_OFF;
    float* Abuf = ws + A_OFF;
    float* Bbuf = ws + BB_OFF;
    float* Wf   = ws + WF_OFF;

    // 0. fold BN into weights (tiny, one block)
    prep_kernel<<<1, 256, 0, stream>>>(w1, g1, b1, rm1, rv1, w2, g2, b2, rm2, rv2,
                                       w3, Wf);

    // 1. base 8x8/s4 box sums (2 output rows per block)
    base_kernel<<<BC * 128, 256, 0, stream>>>(guide, src, S8);

    // 2. pyramid levels 16/32/64 (+ cov/var stats)
    {
        int total = BC * N2 * N2;
        pyr_kernel<<<(total + 255) / 256, 256, 0, stream>>>(S8, S16, CV16, N1, N2,
                                                            1.f / 256.f);
    }
    {
        int total = BC * N3 * N3;
        pyr_kernel<<<(total + 255) / 256, 256, 0, stream>>>(S16, S32, CV32, N2, N3,
                                                            1.f / 1024.f);
    }
    {
        int total = BC * N4 * N4;
        pyr_kernel<<<(total + 255) / 256, 256, 0, stream>>>(S32, S64, CV64, N3, N4,
                                                            1.f / 4096.f);
    }

    // 3. fused gather + MLP -> A, bb @255^2
    {
        int total = NB * N1 * N1;
        mlp_kernel<<<(total + 255) / 256, 256, 0, stream>>>(
            S8, CV16, CV32, CV64, Wf, Abuf, Bbuf);
    }

    // 4. fused upsample + apply
    final_kernel<<<BC * HH, 256, 0, stream>>>(guide, Abuf, Bbuf, out);
}